// Round 13
// baseline (227.824 us; speedup 1.0000x reference)
//
#include <hip/hip_runtime.h>
#include <hip/hip_bf16.h>
#include <math.h>

#define NV  10
#define H1  64
#define H2  32

typedef __attribute__((ext_vector_type(8))) short bf16x8;
typedef __attribute__((ext_vector_type(4))) float f32x4;
typedef __attribute__((ext_vector_type(2))) float f32x2;
typedef __attribute__((ext_vector_type(4))) unsigned int u32x4;

union frag_u { bf16x8 f; u32x4 u; unsigned int w[4]; };

#define MFMA(a,b,c) __builtin_amdgcn_mfma_f32_16x16x32_bf16(a, b, c, 0, 0, 0)

__device__ __forceinline__ unsigned short f2bf(float f) {
    union { __hip_bfloat16 h; unsigned short u; } cv;
    cv.h = __float2bfloat16(f);   // RNE; pairs lower to v_cvt_pk_bf16_f32
    return cv.u;
}
__device__ __forceinline__ unsigned int pack2(float lo, float hi) {
    return (unsigned)f2bf(lo) | ((unsigned)f2bf(hi) << 16);
}

// v2f32 fma -> llvm.fma.v2f32 -> v_pk_fma_f32 (gfx950 has packed-fp32 ops).
// Compiler-selected packed math: encoding/op_sel owned by the backend
// (round 11's hand-written VOP3P asm had wrong hi-half semantics -> 0.143).
__device__ __forceinline__ f32x2 vfma2(f32x2 a, f32x2 b, f32x2 c) {
    return __builtin_elementwise_fma(a, b, c);
}

// Packed GELU: per-element numerics IDENTICAL to rounds 8-10 scalar version
// (deg-11 odd poly for erf(x/sqrt2) on [-3,3]; |x|>3 -> max(x,0)).
__device__ __forceinline__ f32x2 gelu2(f32x2 x) {
    const f32x2 cA = {-4.6113e-6f,    -4.6113e-6f};
    const f32x2 cB = { 1.47439e-4f,    1.47439e-4f};
    const f32x2 cC = {-2.136050e-3f,  -2.136050e-3f};
    const f32x2 cD = { 1.966256e-2f,   1.966256e-2f};
    const f32x2 cE = {-1.3288786e-1f, -1.3288786e-1f};
    const f32x2 cF = { 7.9788456e-1f,  7.9788456e-1f};
    f32x2 p;
    p[0] = __builtin_amdgcn_fmed3f(x[0], -3.0f, 3.0f);
    p[1] = __builtin_amdgcn_fmed3f(x[1], -3.0f, 3.0f);
    f32x2 p2 = p * p;                 // v_pk_mul_f32
    f32x2 t  = vfma2(p2, cA, cB);     // v_pk_fma_f32 chain
    t        = vfma2(p2, t, cC);
    t        = vfma2(p2, t, cD);
    t        = vfma2(p2, t, cE);
    t        = vfma2(p2, t, cF);
    f32x2 P  = p * t;
    f32x2 hx = x * 0.5f;
    f32x2 y  = vfma2(hx, P, hx);
    y[0] = (__builtin_fabsf(x[0]) > 3.0f) ? fmaxf(x[0], 0.0f) : y[0];
    y[1] = (__builtin_fabsf(x[1]) > 3.0f) ? fmaxf(x[1], 0.0f) : y[1];
    return y;
}

// ---------------------------------------------------------------------------
// Prep (1 block): adjacency mask -> Wout; W1 (adjacency+bias folded) and W2
// rearranged into exact MFMA A-fragment order as bf16 in ws. (round-8 layout)
// ---------------------------------------------------------------------------
__global__ void prep_W(const float* __restrict__ Wl,
                       const float* __restrict__ W1,
                       const float* __restrict__ b1,
                       const float* __restrict__ W2,
                       float* __restrict__ Wout,
                       unsigned short* __restrict__ a1,
                       unsigned short* __restrict__ a2) {
    __shared__ float W[100];
    __shared__ float thrv;
    int t = threadIdx.x;   // 256 threads
    if (t < 100) {
        int i = t / NV, j = t % NV;
        float w = 1.0f / (1.0f + expf(-Wl[t]));
        if (i == j) w = 0.0f;
        W[t] = w;
    }
    __syncthreads();
    if (t < 100) {
        float v = W[t];
        int cnt = 0;
        #pragma unroll
        for (int k = 0; k < 100; ++k) cnt += (W[k] > v) ? 1 : 0;
        if (cnt == 29) thrv = v;   // exactly 29 strictly greater == 30th largest
    }
    __syncthreads();
    if (t < 100) {
        float v = W[t];
        float m = (v >= thrv) ? v : 0.0f;
        Wout[t] = m;
        W[t] = m;
    }
    __syncthreads();
    // a1 fragments: row h=16t+(lane&15), k=(lane>>4)*8+b; k==10 is the bias slot
    for (int n = t; n < 20480; n += 256) {
        int b = n & 7, l = (n >> 3) & 63, tt = (n >> 9) & 3, j = n >> 11;
        int h = 16 * tt + (l & 15);
        int k = ((l >> 4) << 3) + b;
        float val = 0.0f;
        if (k < 10)       val = W1[j * 640 + h * 10 + k] * W[k * NV + j];
        else if (k == 10) val = b1[j * 64 + h];
        a1[n] = f2bf(val);
    }
    // a2 fragments: row o=16t2+(lane&15), h=32ks+(lane>>4)*8+b
    for (int n = t; n < 20480; n += 256) {
        int b = n & 7, l = (n >> 3) & 63, ks = (n >> 9) & 1, t2 = (n >> 10) & 1, j = n >> 11;
        int o = 16 * t2 + (l & 15);
        int h = 32 * ks + ((l >> 4) << 3) + b;
        a2[n] = f2bf(W2[j * 2048 + o * 64 + h]);
    }
}

// ---------------------------------------------------------------------------
// Main: each wave owns ONE j, grid-strides over 16-sample tiles; all weights
// for that j in registers (8 A-frags, b2/W3 packed pairs, b3[j]).
// Round 12 = round 10 structure + compiler-packed v2f32 GELU (round 11's
// inline-asm VOP3P replaced by __builtin_elementwise_fma on f32x2).
// ---------------------------------------------------------------------------
__global__ __launch_bounds__(256, 4) void ncd_mfma(
    const float* __restrict__ X,            // [B,10]
    const unsigned short* __restrict__ a1u, // frag-ordered W1eff+bias (bf16)
    const unsigned short* __restrict__ a2u, // frag-ordered W2 (bf16)
    const float* __restrict__ b2,           // [10,32]
    const float* __restrict__ W3,           // [10,32]
    const float* __restrict__ b3,           // [10]
    float* __restrict__ out,                // [B,10]
    int Bn, int ntiles, int jstride)        // jstride = total_waves/10
{
    __shared__ unsigned xlds[4][512];       // per-wave 2KB handoff buffer

    const int wave = threadIdx.x >> 6;
    const int lane = threadIdx.x & 63;
    const int q = lane >> 4;
    const int s = lane & 15;

    const int gw = blockIdx.x * 4 + wave;   // global wave id
    const int j  = gw % NV;                 // this wave's MLP index
    const int t0 = gw / NV;                 // first tile

    // ---- hoist all j-weights into registers (once per wave) ----
    const bf16x8* A1 = (const bf16x8*)a1u;
    const bf16x8* A2 = (const bf16x8*)a2u;
    bf16x8 af1[4], af2[4];
    #pragma unroll
    for (int tt = 0; tt < 4; ++tt) af1[tt] = A1[(j * 4 + tt) * 64 + lane];
    #pragma unroll
    for (int t2 = 0; t2 < 2; ++t2)
        #pragma unroll
        for (int ks = 0; ks < 2; ++ks)
            af2[t2 * 2 + ks] = A2[((j * 2 + t2) * 2 + ks) * 64 + lane];
    // b2 / W3 slices as packed pairs
    f32x2 b2p[4], w3p[4];
    #pragma unroll
    for (int t2 = 0; t2 < 2; ++t2) {
        float4 bv = *(const float4*)(b2 + j * 32 + 16 * t2 + 4 * q);
        float4 wv = *(const float4*)(W3 + j * 32 + 16 * t2 + 4 * q);
        b2p[t2 * 2    ] = (f32x2){bv.x, bv.y};
        b2p[t2 * 2 + 1] = (f32x2){bv.z, bv.w};
        w3p[t2 * 2    ] = (f32x2){wv.x, wv.y};
        w3p[t2 * 2 + 1] = (f32x2){wv.z, wv.w};
    }
    const float b3j = b3[j];

    unsigned* wb = xlds[wave];
    const int sw = (s & 7) << 2;
    const f32x4 zf = {0.0f, 0.0f, 0.0f, 0.0f};

    #pragma unroll 1
    for (int tile = t0; tile < ntiles; tile += jstride) {
        const int sbase = tile * 16;

        // --- B-frag of GEMM1: X row s, k = q*8+b (k=10 -> bias slot 1.0) ---
        int row = sbase + s; if (row > Bn - 1) row = Bn - 1;
        const float* xr = X + (size_t)row * 10;
        frag_u xb;
        if (q == 0) {
            float2 v0 = *(const float2*)(xr + 0), v1 = *(const float2*)(xr + 2);
            float2 v2 = *(const float2*)(xr + 4), v3 = *(const float2*)(xr + 6);
            xb.w[0] = pack2(v0.x, v0.y); xb.w[1] = pack2(v1.x, v1.y);
            xb.w[2] = pack2(v2.x, v2.y); xb.w[3] = pack2(v3.x, v3.y);
        } else if (q == 1) {
            float2 v4 = *(const float2*)(xr + 8);
            xb.w[0] = pack2(v4.x, v4.y);
            xb.w[1] = pack2(1.0f, 0.0f);          // k=10: bias slot
            xb.w[2] = 0u; xb.w[3] = 0u;
        } else {
            xb.w[0] = xb.w[1] = xb.w[2] = xb.w[3] = 0u;
        }

        // --- GEMM1: 4 h-tiles ---
        f32x4 acc[4];
        #pragma unroll
        for (int tt = 0; tt < 4; ++tt) acc[tt] = MFMA(af1[tt], xb.f, zf);

        // --- packed GELU + pack + swizzled per-wave LDS write ---
        #pragma unroll
        for (int tt = 0; tt < 4; ++tt) {
            f32x2 g01 = gelu2((f32x2){acc[tt][0], acc[tt][1]});
            f32x2 g23 = gelu2((f32x2){acc[tt][2], acc[tt][3]});
            int w0 = 8 * tt + 2 * q;
            wb[s * 32 + ((w0    ) ^ sw)] = pack2(g01[0], g01[1]);
            wb[s * 32 + ((w0 + 1) ^ sw)] = pack2(g23[0], g23[1]);
        }

        // --- GEMM2: 2 o-tiles x 2 K-steps ---
        f32x4 acc2[2] = {zf, zf};
        #pragma unroll
        for (int ks = 0; ks < 2; ++ks) {
            frag_u bfg;
            bfg.u = *(const u32x4*)&wb[s * 32 + ((16 * ks + 4 * q) ^ sw)];
            #pragma unroll
            for (int t2 = 0; t2 < 2; ++t2)
                acc2[t2] = MFMA(af2[t2 * 2 + ks], bfg.f, acc2[t2]);
        }

        // --- packed bias + GELU + head dot; then quarter-lane reduce ---
        f32x2 pacc = (f32x2){0.0f, 0.0f};
        #pragma unroll
        for (int t2 = 0; t2 < 2; ++t2) {
            f32x2 v01 = (f32x2){acc2[t2][0], acc2[t2][1]} + b2p[t2 * 2    ];
            f32x2 v23 = (f32x2){acc2[t2][2], acc2[t2][3]} + b2p[t2 * 2 + 1];
            pacc = vfma2(gelu2(v01), w3p[t2 * 2    ], pacc);
            pacc = vfma2(gelu2(v23), w3p[t2 * 2 + 1], pacc);
        }
        float partial = pacc[0] + pacc[1];
        partial += __shfl_xor(partial, 16);
        partial += __shfl_xor(partial, 32);
        float rj = partial + b3j;
        if (lane < 16 && sbase + lane < Bn) {
            out[(size_t)(sbase + lane) * 10 + j] = rj;
        }
    }
}

extern "C" void kernel_launch(void* const* d_in, const int* in_sizes, int n_in,
                              void* d_out, int out_size, void* d_ws, size_t ws_size,
                              hipStream_t stream) {
    const float* X  = (const float*)d_in[0];
    const float* Wl = (const float*)d_in[1];
    const float* W1 = (const float*)d_in[2];
    const float* b1 = (const float*)d_in[3];
    const float* W2 = (const float*)d_in[4];
    const float* b2 = (const float*)d_in[5];
    const float* W3 = (const float*)d_in[6];
    const float* b3 = (const float*)d_in[7];
    float* out = (float*)d_out;

    int B = in_sizes[0] / NV;                 // 500000
    float* Wout = out + (size_t)B * NV;       // output #2 (10x10 W) at the tail
    unsigned short* a1 = (unsigned short*)d_ws;        // 20480 bf16 = 40KB
    unsigned short* a2 = a1 + 20480;                   // 20480 bf16 = 40KB

    hipLaunchKernelGGL(prep_W, dim3(1), dim3(256), 0, stream,
                       Wl, W1, b1, W2, Wout, a1, a2);

    int ntiles = (B + 15) / 16;               // 31250
    const int blocks = 9765;                  // 39060 waves (mult of 5)
    const int jstride = blocks * 4 / NV;
    hipLaunchKernelGGL(ncd_mfma, dim3(blocks), dim3(256), 0, stream,
                       X, a1, a2, b2, W3, b3, out, B, ntiles, jstride);
}

// Round 14
// 219.609 us; speedup vs baseline: 1.0374x; 1.0374x over previous
//
#include <hip/hip_runtime.h>
#include <hip/hip_bf16.h>
#include <math.h>

#define NV  10
#define H1  64
#define H2  32

typedef __attribute__((ext_vector_type(8))) short bf16x8;
typedef __attribute__((ext_vector_type(4))) float f32x4;
typedef __attribute__((ext_vector_type(2))) float f32x2;
typedef __attribute__((ext_vector_type(4))) unsigned int u32x4;

union frag_u { bf16x8 f; u32x4 u; unsigned int w[4]; };

#define MFMA(a,b,c) __builtin_amdgcn_mfma_f32_16x16x32_bf16(a, b, c, 0, 0, 0)

__device__ __forceinline__ unsigned short f2bf(float f) {
    union { __hip_bfloat16 h; unsigned short u; } cv;
    cv.h = __float2bfloat16(f);   // RNE; pairs lower to v_cvt_pk_bf16_f32
    return cv.u;
}
__device__ __forceinline__ unsigned int pack2(float lo, float hi) {
    return (unsigned)f2bf(lo) | ((unsigned)f2bf(hi) << 16);
}

// v2f32 ops -> v_pk_{fma,mul,add}_f32 (compiler-selected; round-11 asm bug avoided)
__device__ __forceinline__ f32x2 vfma2(f32x2 a, f32x2 b, f32x2 c) {
    return __builtin_elementwise_fma(a, b, c);
}

// Packed GELU: per-element numerics identical to the scalar rounds 8-10
// (deg-11 odd poly for erf(x/sqrt2) on [-3,3]; |x|>3 -> max(x,0)).
__device__ __forceinline__ f32x2 gelu2(f32x2 x) {
    const f32x2 cA = {-4.6113e-6f,    -4.6113e-6f};
    const f32x2 cB = { 1.47439e-4f,    1.47439e-4f};
    const f32x2 cC = {-2.136050e-3f,  -2.136050e-3f};
    const f32x2 cD = { 1.966256e-2f,   1.966256e-2f};
    const f32x2 cE = {-1.3288786e-1f, -1.3288786e-1f};
    const f32x2 cF = { 7.9788456e-1f,  7.9788456e-1f};
    f32x2 p;
    p[0] = __builtin_amdgcn_fmed3f(x[0], -3.0f, 3.0f);
    p[1] = __builtin_amdgcn_fmed3f(x[1], -3.0f, 3.0f);
    f32x2 p2 = p * p;
    f32x2 t  = vfma2(p2, cA, cB);
    t        = vfma2(p2, t, cC);
    t        = vfma2(p2, t, cD);
    t        = vfma2(p2, t, cE);
    t        = vfma2(p2, t, cF);
    f32x2 P  = p * t;
    f32x2 hx = x * 0.5f;
    f32x2 y  = vfma2(hx, P, hx);
    y[0] = (__builtin_fabsf(x[0]) > 3.0f) ? fmaxf(x[0], 0.0f) : y[0];
    y[1] = (__builtin_fabsf(x[1]) > 3.0f) ? fmaxf(x[1], 0.0f) : y[1];
    return y;
}

// ---------------------------------------------------------------------------
// Prep (1 block): adjacency mask -> Wout; W1 (adjacency+bias folded) and W2
// rearranged into exact MFMA A-fragment order as bf16 in ws. (round-8 layout)
// ---------------------------------------------------------------------------
__global__ void prep_W(const float* __restrict__ Wl,
                       const float* __restrict__ W1,
                       const float* __restrict__ b1,
                       const float* __restrict__ W2,
                       float* __restrict__ Wout,
                       unsigned short* __restrict__ a1,
                       unsigned short* __restrict__ a2) {
    __shared__ float W[100];
    __shared__ float thrv;
    int t = threadIdx.x;   // 256 threads
    if (t < 100) {
        int i = t / NV, j = t % NV;
        float w = 1.0f / (1.0f + expf(-Wl[t]));
        if (i == j) w = 0.0f;
        W[t] = w;
    }
    __syncthreads();
    if (t < 100) {
        float v = W[t];
        int cnt = 0;
        #pragma unroll
        for (int k = 0; k < 100; ++k) cnt += (W[k] > v) ? 1 : 0;
        if (cnt == 29) thrv = v;   // exactly 29 strictly greater == 30th largest
    }
    __syncthreads();
    if (t < 100) {
        float v = W[t];
        float m = (v >= thrv) ? v : 0.0f;
        Wout[t] = m;
        W[t] = m;
    }
    __syncthreads();
    // a1 fragments: row h=16t+(lane&15), k=(lane>>4)*8+b; k==10 is the bias slot
    for (int n = t; n < 20480; n += 256) {
        int b = n & 7, l = (n >> 3) & 63, tt = (n >> 9) & 3, j = n >> 11;
        int h = 16 * tt + (l & 15);
        int k = ((l >> 4) << 3) + b;
        float val = 0.0f;
        if (k < 10)       val = W1[j * 640 + h * 10 + k] * W[k * NV + j];
        else if (k == 10) val = b1[j * 64 + h];
        a1[n] = f2bf(val);
    }
    // a2 fragments: row o=16t2+(lane&15), h=32ks+(lane>>4)*8+b
    for (int n = t; n < 20480; n += 256) {
        int b = n & 7, l = (n >> 3) & 63, ks = (n >> 9) & 1, t2 = (n >> 10) & 1, j = n >> 11;
        int o = 16 * t2 + (l & 15);
        int h = 32 * ks + ((l >> 4) << 3) + b;
        a2[n] = f2bf(W2[j * 2048 + o * 64 + h]);
    }
}

// ---------------------------------------------------------------------------
// Main: wave owns one j; processes TWO tiles per loop iteration with
// independent register sets + ping-pong LDS buffers. Round 12 showed the
// kernel is latency-bound (packed GELU cut VALU issue 30%, time flat):
// 2-tile ILP gives each wave two independent ~900-cycle chains so the
// scheduler can fill the stall slots. Tail is branch-free (tile2 clamps to
// tile -> benign duplicate store) so both bodies stay in one basic block.
// ---------------------------------------------------------------------------
__global__ __launch_bounds__(256, 3) void ncd_mfma(
    const float* __restrict__ X,            // [B,10]
    const unsigned short* __restrict__ a1u, // frag-ordered W1eff+bias (bf16)
    const unsigned short* __restrict__ a2u, // frag-ordered W2 (bf16)
    const float* __restrict__ b2,           // [10,32]
    const float* __restrict__ W3,           // [10,32]
    const float* __restrict__ b3,           // [10]
    float* __restrict__ out,                // [B,10]
    int Bn, int ntiles, int jstride)        // jstride = total_waves/10
{
    __shared__ unsigned xlds[4][2][512];    // per-wave 2x2KB ping-pong buffers

    const int wave = threadIdx.x >> 6;
    const int lane = threadIdx.x & 63;
    const int q = lane >> 4;
    const int s = lane & 15;

    const int gw = blockIdx.x * 4 + wave;   // global wave id
    const int j  = gw % NV;                 // this wave's MLP index
    const int t0 = gw / NV;                 // first tile

    // ---- hoist all j-weights into registers (once per wave) ----
    const bf16x8* A1 = (const bf16x8*)a1u;
    const bf16x8* A2 = (const bf16x8*)a2u;
    bf16x8 af1[4], af2[4];
    #pragma unroll
    for (int tt = 0; tt < 4; ++tt) af1[tt] = A1[(j * 4 + tt) * 64 + lane];
    #pragma unroll
    for (int t2 = 0; t2 < 2; ++t2)
        #pragma unroll
        for (int ks = 0; ks < 2; ++ks)
            af2[t2 * 2 + ks] = A2[((j * 2 + t2) * 2 + ks) * 64 + lane];
    f32x2 b2p[4], w3p[4];
    #pragma unroll
    for (int t2 = 0; t2 < 2; ++t2) {
        float4 bv = *(const float4*)(b2 + j * 32 + 16 * t2 + 4 * q);
        float4 wv = *(const float4*)(W3 + j * 32 + 16 * t2 + 4 * q);
        b2p[t2 * 2    ] = (f32x2){bv.x, bv.y};
        b2p[t2 * 2 + 1] = (f32x2){bv.z, bv.w};
        w3p[t2 * 2    ] = (f32x2){wv.x, wv.y};
        w3p[t2 * 2 + 1] = (f32x2){wv.z, wv.w};
    }
    const float b3j = b3[j];
    const f32x4 zf = {0.0f, 0.0f, 0.0f, 0.0f};

    // per-tile body; inlined twice per loop iteration with independent state
    auto do_tile = [&](int tileIdx, unsigned* wb) {
        const int sbase = tileIdx * 16;
        int row = sbase + s; if (row > Bn - 1) row = Bn - 1;
        const float* xr = X + (size_t)row * 10;
        const int sw = (s & 7) << 2;
        frag_u xb;
        if (q == 0) {
            float2 v0 = *(const float2*)(xr + 0), v1 = *(const float2*)(xr + 2);
            float2 v2 = *(const float2*)(xr + 4), v3 = *(const float2*)(xr + 6);
            xb.w[0] = pack2(v0.x, v0.y); xb.w[1] = pack2(v1.x, v1.y);
            xb.w[2] = pack2(v2.x, v2.y); xb.w[3] = pack2(v3.x, v3.y);
        } else if (q == 1) {
            float2 v4 = *(const float2*)(xr + 8);
            xb.w[0] = pack2(v4.x, v4.y);
            xb.w[1] = pack2(1.0f, 0.0f);          // k=10: bias slot
            xb.w[2] = 0u; xb.w[3] = 0u;
        } else {
            xb.w[0] = xb.w[1] = xb.w[2] = xb.w[3] = 0u;
        }

        // GEMM1: 4 h-tiles
        f32x4 acc[4];
        #pragma unroll
        for (int tt = 0; tt < 4; ++tt) acc[tt] = MFMA(af1[tt], xb.f, zf);

        // packed GELU + swizzled per-wave LDS write
        #pragma unroll
        for (int tt = 0; tt < 4; ++tt) {
            f32x2 g01 = gelu2((f32x2){acc[tt][0], acc[tt][1]});
            f32x2 g23 = gelu2((f32x2){acc[tt][2], acc[tt][3]});
            int w0 = 8 * tt + 2 * q;
            wb[s * 32 + ((w0    ) ^ sw)] = pack2(g01[0], g01[1]);
            wb[s * 32 + ((w0 + 1) ^ sw)] = pack2(g23[0], g23[1]);
        }

        // GEMM2: 2 o-tiles x 2 K-steps
        f32x4 acc2[2] = {zf, zf};
        #pragma unroll
        for (int ks = 0; ks < 2; ++ks) {
            frag_u bfg;
            bfg.u = *(const u32x4*)&wb[s * 32 + ((16 * ks + 4 * q) ^ sw)];
            #pragma unroll
            for (int t2 = 0; t2 < 2; ++t2)
                acc2[t2] = MFMA(af2[t2 * 2 + ks], bfg.f, acc2[t2]);
        }

        // packed bias + GELU + head dot; quarter-lane reduce; store
        f32x2 pacc = (f32x2){0.0f, 0.0f};
        #pragma unroll
        for (int t2 = 0; t2 < 2; ++t2) {
            f32x2 v01 = (f32x2){acc2[t2][0], acc2[t2][1]} + b2p[t2 * 2    ];
            f32x2 v23 = (f32x2){acc2[t2][2], acc2[t2][3]} + b2p[t2 * 2 + 1];
            pacc = vfma2(gelu2(v01), w3p[t2 * 2    ], pacc);
            pacc = vfma2(gelu2(v23), w3p[t2 * 2 + 1], pacc);
        }
        float partial = pacc[0] + pacc[1];
        partial += __shfl_xor(partial, 16);
        partial += __shfl_xor(partial, 32);
        float rj = partial + b3j;
        if (lane < 16 && sbase + lane < Bn) {
            out[(size_t)(sbase + lane) * 10 + j] = rj;
        }
    };

    #pragma unroll 1
    for (int tile = t0; tile < ntiles; tile += 2 * jstride) {
        int tile2 = tile + jstride;
        if (tile2 >= ntiles) tile2 = tile;    // branch-free tail: dup compute
        do_tile(tile,  xlds[wave][0]);
        do_tile(tile2, xlds[wave][1]);
    }
}

extern "C" void kernel_launch(void* const* d_in, const int* in_sizes, int n_in,
                              void* d_out, int out_size, void* d_ws, size_t ws_size,
                              hipStream_t stream) {
    const float* X  = (const float*)d_in[0];
    const float* Wl = (const float*)d_in[1];
    const float* W1 = (const float*)d_in[2];
    const float* b1 = (const float*)d_in[3];
    const float* W2 = (const float*)d_in[4];
    const float* b2 = (const float*)d_in[5];
    const float* W3 = (const float*)d_in[6];
    const float* b3 = (const float*)d_in[7];
    float* out = (float*)d_out;

    int B = in_sizes[0] / NV;                 // 500000
    float* Wout = out + (size_t)B * NV;       // output #2 (10x10 W) at the tail
    unsigned short* a1 = (unsigned short*)d_ws;        // 20480 bf16 = 40KB
    unsigned short* a2 = a1 + 20480;                   // 20480 bf16 = 40KB

    hipLaunchKernelGGL(prep_W, dim3(1), dim3(256), 0, stream,
                       Wl, W1, b1, W2, Wout, a1, a2);

    int ntiles = (B + 15) / 16;               // 31250
    const int blocks = 9765;                  // 39060 waves (mult of 5)
    const int jstride = blocks * 4 / NV;      // 3906
    hipLaunchKernelGGL(ncd_mfma, dim3(blocks), dim3(256), 0, stream,
                       X, a1, a2, b2, W3, b3, out, B, ntiles, jstride);
}

// Round 16
// 212.425 us; speedup vs baseline: 1.0725x; 1.0338x over previous
//
#include <hip/hip_runtime.h>
#include <hip/hip_bf16.h>
#include <math.h>

#define NV  10
#define H1  64
#define H2  32

typedef __attribute__((ext_vector_type(8))) short bf16x8;
typedef __attribute__((ext_vector_type(4))) float f32x4;
typedef __attribute__((ext_vector_type(4))) unsigned int u32x4;

union frag_u { bf16x8 f; u32x4 u; unsigned int w[4]; };

#define MFMA(a,b,c) __builtin_amdgcn_mfma_f32_16x16x32_bf16(a, b, c, 0, 0, 0)

__device__ __forceinline__ unsigned short f2bf(float f) {
    union { __hip_bfloat16 h; unsigned short u; } cv;
    cv.h = __float2bfloat16(f);   // RNE
    return cv.u;
}
__device__ __forceinline__ unsigned int pack2(float lo, float hi) {
    return (unsigned)f2bf(lo) | ((unsigned)f2bf(hi) << 16);
}

// GELU: deg-11 odd poly for erf(x/sqrt2) on [-3,3]; |x|>3 -> max(x,0).
// KNOWN-GOOD scalar version (rounds 8-10, absmax 2e-3). Packed-math attempts
// (r11/r12/r14) all failed or were null -- frozen on scalar.
__device__ __forceinline__ float gelu_poly(float x) {
    float p  = __builtin_amdgcn_fmed3f(x, -3.0f, 3.0f);
    float p2 = p * p;
    float t  = __builtin_fmaf(p2, -4.6113e-6f,    1.47439e-4f);
    t        = __builtin_fmaf(p2, t, -2.136050e-3f);
    t        = __builtin_fmaf(p2, t,  1.966256e-2f);
    t        = __builtin_fmaf(p2, t, -1.3288786e-1f);
    t        = __builtin_fmaf(p2, t,  7.9788456e-1f);
    float P  = p * t;
    float hx = 0.5f * x;
    float y  = __builtin_fmaf(hx, P, hx);
    float big = fmaxf(x, 0.0f);
    return (__builtin_fabsf(x) > 3.0f) ? big : y;
}

// ---------------------------------------------------------------------------
// Prep (1 block): adjacency mask -> Wout; W1 (adjacency+bias folded) and W2
// in MFMA A-fragment order (bf16).
// KEY CHANGE vs round 8: A2's K axis is PERMUTED so that GEMM2's B-fragment
// is exactly each lane's own GEMM1 outputs -- MFMA contracts over 32 K-slots,
// and permuting K consistently on A and B leaves D unchanged. Slot k=8*qk+b
// maps to h = 32*ks + (b<4 ? 4*qk+b : 16+4*qk+(b-4)): lane (q,s)'s slots
// {8q..8q+7} are GEMM1's acc[2ks][0..3] (h=32ks+4q+r) and acc[2ks+1][0..3]
// (h=32ks+16+4q+r), both already resident in that lane (C-layout
// row=(lane>>4)*4+reg, m89/m91). The LDS handoff vanishes.
// ---------------------------------------------------------------------------
__global__ void prep_W(const float* __restrict__ Wl,
                       const float* __restrict__ W1,
                       const float* __restrict__ b1,
                       const float* __restrict__ W2,
                       float* __restrict__ Wout,
                       unsigned short* __restrict__ a1,
                       unsigned short* __restrict__ a2) {
    __shared__ float W[100];
    __shared__ float thrv;
    int t = threadIdx.x;   // 256 threads
    if (t < 100) {
        int i = t / NV, j = t % NV;
        float w = 1.0f / (1.0f + expf(-Wl[t]));
        if (i == j) w = 0.0f;
        W[t] = w;
    }
    __syncthreads();
    if (t < 100) {
        float v = W[t];
        int cnt = 0;
        #pragma unroll
        for (int k = 0; k < 100; ++k) cnt += (W[k] > v) ? 1 : 0;
        if (cnt == 29) thrv = v;   // exactly 29 strictly greater == 30th largest
    }
    __syncthreads();
    if (t < 100) {
        float v = W[t];
        float m = (v >= thrv) ? v : 0.0f;
        Wout[t] = m;
        W[t] = m;
    }
    __syncthreads();
    // a1 fragments: row h=16t+(lane&15), k=(lane>>4)*8+b; k==10 is the bias slot
    for (int n = t; n < 20480; n += 256) {
        int b = n & 7, l = (n >> 3) & 63, tt = (n >> 9) & 3, j = n >> 11;
        int h = 16 * tt + (l & 15);
        int k = ((l >> 4) << 3) + b;
        float val = 0.0f;
        if (k < 10)       val = W1[j * 640 + h * 10 + k] * W[k * NV + j];
        else if (k == 10) val = b1[j * 64 + h];
        a1[n] = f2bf(val);
    }
    // a2 fragments with K-permutation (see header comment):
    // row o=16*t2+(l&15); slot (qk=l>>4, b) -> h = 32*ks + hrel
    for (int n = t; n < 20480; n += 256) {
        int b = n & 7, l = (n >> 3) & 63, ks = (n >> 9) & 1, t2 = (n >> 10) & 1, j = n >> 11;
        int o  = 16 * t2 + (l & 15);
        int qk = l >> 4;
        int hrel = (b < 4) ? (4 * qk + b) : (16 + 4 * qk + (b - 4));
        int h  = 32 * ks + hrel;
        a2[n] = f2bf(W2[j * 2048 + o * 64 + h]);
    }
}

// ---------------------------------------------------------------------------
// Main: 1 wave = 16 samples (round-8 structure: best measured, 78% occ).
// Change vs round 8: NO LDS handoff between GEMMs -- GEMM2's B-frag is
// built in-register from this lane's own GELU'd acc values (K-permuted A2).
// Removes 8 ds_write + 2 ds_read_b128 + swizzle math + 2 lgkmcnt waits +
// 5M bank-conflict cycles per dispatch.
// ---------------------------------------------------------------------------
__global__ __launch_bounds__(256, 4) void ncd_mfma(
    const float* __restrict__ X,            // [B,10]
    const unsigned short* __restrict__ a1u, // frag-ordered W1eff+bias (bf16)
    const unsigned short* __restrict__ a2u, // frag-ordered, K-permuted W2 (bf16)
    const float* __restrict__ b2,           // [10,32]
    const float* __restrict__ W3,           // [10,32]
    const float* __restrict__ b3,           // [10]
    float* __restrict__ out,                // [B,10]
    int Bn, int ntiles)
{
    __shared__ float b2s[320];
    __shared__ float w3s[320];
    for (int i = threadIdx.x; i < 320; i += 256) { b2s[i] = b2[i]; w3s[i] = W3[i]; }
    __syncthreads();

    const int wave = threadIdx.x >> 6;
    const int lane = threadIdx.x & 63;
    const int q = lane >> 4;
    const int s = lane & 15;
    const int tile = blockIdx.x * 4 + wave;
    if (tile >= ntiles) return;
    const int sbase = tile * 16;

    // --- B-frag of GEMM1: X row s, k = q*8+b (k=10 -> bias slot 1.0) ---
    int row = sbase + s; if (row > Bn - 1) row = Bn - 1;
    const float* xr = X + (size_t)row * 10;
    frag_u xb;
    if (q == 0) {
        float2 v0 = *(const float2*)(xr + 0), v1 = *(const float2*)(xr + 2);
        float2 v2 = *(const float2*)(xr + 4), v3 = *(const float2*)(xr + 6);
        xb.w[0] = pack2(v0.x, v0.y); xb.w[1] = pack2(v1.x, v1.y);
        xb.w[2] = pack2(v2.x, v2.y); xb.w[3] = pack2(v3.x, v3.y);
    } else if (q == 1) {
        float2 v4 = *(const float2*)(xr + 8);
        xb.w[0] = pack2(v4.x, v4.y);
        xb.w[1] = pack2(1.0f, 0.0f);          // k=10: bias slot
        xb.w[2] = 0u; xb.w[3] = 0u;
    } else {
        xb.w[0] = xb.w[1] = xb.w[2] = xb.w[3] = 0u;
    }

    const bf16x8* A1 = (const bf16x8*)a1u;
    const bf16x8* A2 = (const bf16x8*)a2u;
    const f32x4 zf = {0.0f, 0.0f, 0.0f, 0.0f};

    #pragma unroll 1
    for (int j = 0; j < NV; ++j) {
        // --- GEMM1: 4 h-tiles ---
        f32x4 acc[4];
        #pragma unroll
        for (int tt = 0; tt < 4; ++tt) {
            frag_u af; af.f = A1[(j * 4 + tt) * 64 + lane];
            acc[tt] = MFMA(af.f, xb.f, zf);
        }

        // --- GELU + in-register B-frag build (no LDS; K-permuted A2) ---
        frag_u pb0, pb1;
        pb0.w[0] = pack2(gelu_poly(acc[0][0]), gelu_poly(acc[0][1]));
        pb0.w[1] = pack2(gelu_poly(acc[0][2]), gelu_poly(acc[0][3]));
        pb0.w[2] = pack2(gelu_poly(acc[1][0]), gelu_poly(acc[1][1]));
        pb0.w[3] = pack2(gelu_poly(acc[1][2]), gelu_poly(acc[1][3]));
        pb1.w[0] = pack2(gelu_poly(acc[2][0]), gelu_poly(acc[2][1]));
        pb1.w[1] = pack2(gelu_poly(acc[2][2]), gelu_poly(acc[2][3]));
        pb1.w[2] = pack2(gelu_poly(acc[3][0]), gelu_poly(acc[3][1]));
        pb1.w[3] = pack2(gelu_poly(acc[3][2]), gelu_poly(acc[3][3]));

        // --- GEMM2: 2 o-tiles x 2 K-steps ---
        f32x4 acc2[2] = {zf, zf};
        #pragma unroll
        for (int t2 = 0; t2 < 2; ++t2) {
            frag_u af0; af0.f = A2[((j * 2 + t2) * 2 + 0) * 64 + lane];
            acc2[t2] = MFMA(af0.f, pb0.f, acc2[t2]);
        }
        #pragma unroll
        for (int t2 = 0; t2 < 2; ++t2) {
            frag_u af1; af1.f = A2[((j * 2 + t2) * 2 + 1) * 64 + lane];
            acc2[t2] = MFMA(af1.f, pb1.f, acc2[t2]);
        }

        // --- bias + GELU + head dot + quarter-lane reduce ---
        float partial = 0.0f;
        #pragma unroll
        for (int t2 = 0; t2 < 2; ++t2) {
            float4 b2v = *(const float4*)&b2s[j * 32 + 16 * t2 + 4 * q];
            float4 w3v = *(const float4*)&w3s[j * 32 + 16 * t2 + 4 * q];
            partial += gelu_poly(acc2[t2][0] + b2v.x) * w3v.x;
            partial += gelu_poly(acc2[t2][1] + b2v.y) * w3v.y;
            partial += gelu_poly(acc2[t2][2] + b2v.z) * w3v.z;
            partial += gelu_poly(acc2[t2][3] + b2v.w) * w3v.w;
        }
        partial += __shfl_xor(partial, 16);
        partial += __shfl_xor(partial, 32);
        float rj = partial + b3[j];
        if (lane < 16 && sbase + lane < Bn) {
            out[(size_t)(sbase + lane) * 10 + j] = rj;
        }
    }
}

extern "C" void kernel_launch(void* const* d_in, const int* in_sizes, int n_in,
                              void* d_out, int out_size, void* d_ws, size_t ws_size,
                              hipStream_t stream) {
    const float* X  = (const float*)d_in[0];
    const float* Wl = (const float*)d_in[1];
    const float* W1 = (const float*)d_in[2];
    const float* b1 = (const float*)d_in[3];
    const float* W2 = (const float*)d_in[4];
    const float* b2 = (const float*)d_in[5];
    const float* W3 = (const float*)d_in[6];
    const float* b3 = (const float*)d_in[7];
    float* out = (float*)d_out;

    int B = in_sizes[0] / NV;                 // 500000
    float* Wout = out + (size_t)B * NV;       // output #2 (10x10 W) at the tail
    unsigned short* a1 = (unsigned short*)d_ws;        // 20480 bf16 = 40KB
    unsigned short* a2 = a1 + 20480;                   // 20480 bf16 = 40KB

    hipLaunchKernelGGL(prep_W, dim3(1), dim3(256), 0, stream,
                       Wl, W1, b1, W2, Wout, a1, a2);

    int ntiles = (B + 15) / 16;               // 31250
    int blocks = (ntiles + 3) / 4;            // round-8 grid: 1 wave = 1 tile
    hipLaunchKernelGGL(ncd_mfma, dim3(blocks), dim3(256), 0, stream,
                       X, a1, a2, b2, W3, b3, out, B, ntiles);
}